// Round 13
// baseline (196.039 us; speedup 1.0000x reference)
//
#include <hip/hip_runtime.h>
#include <stdint.h>

typedef int v4i __attribute__((ext_vector_type(4)));

#define EPS_F32 1.1920928955078125e-07f   // np.finfo(float32).eps = 2^-23

// ---------------------------------------------------------------------------
// Fused quant kernel: blocks [0,M) do per-token X quant (row-major out),
// blocks [M,M+DOUT) do per-out-channel W quant writing the PACKED layout:
//   Wq[g][kb][col] : g = o>>4 (channel group), kb = k-byte-chunk (16B), col =
//   o&15.  16B chunk of row o at k-range [kb*16,kb*16+16) lives at byte
//   g*65536 + kb*256 + col*16.  This makes the GEMM's per-wave B-fragment
//   load a single contiguous 1KB burst (fixes r11's 4096-stride scatter).
// ---------------------------------------------------------------------------
__global__ __launch_bounds__(256) void quant_kernel(
    const float* __restrict__ X, const float* __restrict__ W,
    const float* __restrict__ ss,
    int8_t* __restrict__ Xq, float* __restrict__ xs,
    int8_t* __restrict__ Wq, float* __restrict__ ws,
    int DIN, int M)
{
    const int bid = blockIdx.x;
    const int tid = threadIdx.x;
    const bool isX = bid < M;
    const float* row = isX ? X + (size_t)bid * DIN
                           : W + (size_t)(bid - M) * DIN;

    float4 v[4];
    float amax = 0.f;
#pragma unroll
    for (int c = 0; c < 4; ++c) {
        const int k = c * 1024 + tid * 4;
        float4 xv = *(const float4*)(row + k);
        float4 sv = *(const float4*)(ss + k);
        float4 q;
        if (isX) { q.x = xv.x / sv.x; q.y = xv.y / sv.y;
                   q.z = xv.z / sv.z; q.w = xv.w / sv.w; }
        else     { q.x = xv.x * sv.x; q.y = xv.y * sv.y;
                   q.z = xv.z * sv.z; q.w = xv.w * sv.w; }
        v[c] = q;
        amax = fmaxf(amax, fmaxf(fmaxf(fabsf(q.x), fabsf(q.y)),
                                 fmaxf(fabsf(q.z), fabsf(q.w))));
    }
    __shared__ float red[4];
    for (int off = 32; off; off >>= 1) amax = fmaxf(amax, __shfl_xor(amax, off));
    const int lane = tid & 63, w = tid >> 6;
    if (lane == 0) red[w] = amax;
    __syncthreads();
    amax = fmaxf(fmaxf(red[0], red[1]), fmaxf(red[2], red[3]));

    float scale, lo;
    if (isX) { scale = fmaxf(amax, 1e-5f) / 127.0f;      lo = -127.f; }
    else     { scale = fmaxf(amax / 127.5f, EPS_F32);    lo = -128.f; }
    if (tid == 0) { if (isX) xs[bid] = scale; else ws[bid - M] = scale; }

    if (isX) {
        int* qout = (int*)(Xq + (size_t)bid * DIN);
#pragma unroll
        for (int c = 0; c < 4; ++c) {
            float4 q = v[c];
            int b0 = (int)fminf(fmaxf(rintf(q.x / scale), lo), 127.f);
            int b1 = (int)fminf(fmaxf(rintf(q.y / scale), lo), 127.f);
            int b2 = (int)fminf(fmaxf(rintf(q.z / scale), lo), 127.f);
            int b3 = (int)fminf(fmaxf(rintf(q.w / scale), lo), 127.f);
            qout[c * 256 + tid] = (b0 & 255) | ((b1 & 255) << 8) |
                                  ((b2 & 255) << 16) | ((b3 & 255) << 24);
        }
    } else {
        const int o = bid - M;
        // packed: int addr = (o>>4)*16384 + kb*64 + (o&15)*4 + (tid&3),
        // kb = c*64 + (tid>>2)   (this thread's ints cover k = c*1024+tid*4)
        int* qW = (int*)Wq + (size_t)(o >> 4) * 16384 + ((o & 15) << 2) + (tid & 3);
#pragma unroll
        for (int c = 0; c < 4; ++c) {
            float4 q = v[c];
            int b0 = (int)fminf(fmaxf(rintf(q.x / scale), lo), 127.f);
            int b1 = (int)fminf(fmaxf(rintf(q.y / scale), lo), 127.f);
            int b2 = (int)fminf(fmaxf(rintf(q.z / scale), lo), 127.f);
            int b3 = (int)fminf(fmaxf(rintf(q.w / scale), lo), 127.f);
            qW[(c * 64 + (tid >> 2)) * 64] = (b0 & 255) | ((b1 & 255) << 8) |
                                             ((b2 & 255) << 16) | ((b3 & 255) << 24);
        }
    }
}

// ---------------------------------------------------------------------------
// Persistent 2-tile int8 NT GEMM, 256x256 tiles, BKB=128, 8 waves (2x4),
// mfma_i32_16x16x64_i8.  Grid = 256 (1 block/CU).
//
// ROUND 13: A through LDS (dbuf 2x32KB, proven r7 path); B loaded directly
// from the PACKED Wq into registers — per-wave fragment load = 1KB
// contiguous from the L2-hot panel (1MB, reused across both segs).
// LDS per kt: 128 ds_read_b128 (~1536cy) + 32KB DMA (~400cy) < MFMA 2613cy.
//
// Per kt (sync skeleton = r7, proven; B is register-dest -> no new hazards):
//   P0: 4 A-stages(next tile,buf^1) ; MFMA(aLo x bF[0,1])       [acc 0..3][0,1]
//   P1: read aHi (cur buf, LDS)     ; MFMA(aLo x bF[2,3])       [acc 0..3][2,3]
//   P2: MFMA(aHi x bF[0,1])                                     [acc 4..7][0,1]
//       vmcnt(0) + s_barrier   (A stages landed; buf^1 published)
//   P3: load bF[0,1](next, global)  [WAR-clean: bF[0,1] last used P2]
//       read aLo(next buf, LDS)
//       MFMA(aHi x bF[2,3])                                     [acc 4..7][2,3]
//       load bF[2,3](next, global)  [after their last use]
// First-use cover: bF[0,1] used P0(next) (~full P3 ahead); bF[2,3] used
// P1(next) (P0 cluster ahead) — both > L2 latency.  Compiler inserts vmcnt
// waits before register uses.  P2's vmcnt(0) sees only the 4 A-stages
// outstanding (B loads of this kt were consumed at P0/P1).  Last kt pf=false
// skips stages/loads/reads (vmcnt(0) no-op).  KT=32 even -> seamless seg
// rollover (kt31-seg0 targets seg1-kt0; epilogue stores drain at seg1-kt0's
// vmcnt(0)).
// ---------------------------------------------------------------------------
#define BM 256
#define BN 256
#define BKB 128

#define MFMA __builtin_amdgcn_mfma_i32_16x16x64_i8

__global__ __launch_bounds__(512, 2) void gemm_i8_kernel(
    const int8_t* __restrict__ Xq, const int8_t* __restrict__ Wq,
    const float* __restrict__ xs, const float* __restrict__ ws,
    const float* __restrict__ bias, float* __restrict__ Y,
    int M, int N, int K)
{
    __shared__ __align__(16) int8_t smem[65536];   // A only: 2 x 32 KiB

    const int tid  = threadIdx.x;
    const int lane = tid & 63;
    const int w    = tid >> 6;
    const int wrow = w >> 2, wcol = w & 3;

    // 256 blocks; XCD-aware: each XCD owns an 8x8 rect of the 32x16 tile grid.
    const int bid    = blockIdx.x;
    const int xcd    = bid & 7, idx = bid >> 3;        // idx in [0,32)
    const int bmBase = (xcd >> 1) * 8 + (idx >> 3);    // seg0 bm; seg1 = +4
    const int bn     = (xcd & 1) * 8 + (idx & 7);

    const int srcSwz = ((lane & 7) ^ (lane >> 3)) << 4;  // A staging source swizzle
    const int chnk0  = ((lane >> 4) ^ (lane & 7)) << 4;  // A frag read, k-slice 0
    const int chnk1  = chnk0 ^ 64;                       // k-slice 1
    const int aRB = ((wrow << 6) + (lane & 15)) << 7;    // A frag row-byte base

    auto STAGE = [&](const int8_t* gtile, int region, int rowStart) {
        const int8_t* src = gtile +
            (size_t)(rowStart + (w << 3) + (lane >> 3)) * K + srcSwz;
        __builtin_amdgcn_global_load_lds(
            (const __attribute__((address_space(1))) void*)src,
            (__attribute__((address_space(3))) void*)(smem + region + ((rowStart + (w << 3)) << 7)),
            16, 0, 0);
    };

    v4i acc[8][4] = {};
    v4i aLo[4][2], aHi[4][2];   // A m-frags (lo = rows 0..63 of wave tile)
    v4i bF[4][2];               // B n-frags 0..3 x k-chunks, direct from L2

    const int KT = K / BKB;   // 32
    const int rowb = (lane >> 4) << 2;
    const int col  = lane & 15;

    // B fragment per-lane base pointers into packed Wq:
    // frag nj -> group gj = bn*16 + (nj>>1)*8 + wcol*2 + (nj&1);
    // lane byte = gj*65536 + (lane>>4)*256 + (lane&15)*16; per kt += 2048,
    // chunk1 at +1024.  Wave footprint per load = 1KB contiguous.
    const int8_t* bP[4];
#pragma unroll
    for (int nj = 0; nj < 4; ++nj) {
        const int gj = (bn << 4) + ((nj >> 1) << 3) + (wcol << 1) + (nj & 1);
        bP[nj] = Wq + ((size_t)gj << 16) + ((lane >> 4) << 8) + ((lane & 15) << 4);
    }

    // prologue: stage A(seg0,kt0) -> buf0; load B(kt0); read aLo(kt0)
    {
        const int8_t* aT0 = Xq + (size_t)bmBase * BM * K;
        STAGE(aT0, 0, 0);   STAGE(aT0, 0, 64);
        STAGE(aT0, 0, 128); STAGE(aT0, 0, 192);
#pragma unroll
        for (int nj = 0; nj < 4; ++nj) {
            bF[nj][0] = *(const v4i*)(bP[nj]);
            bF[nj][1] = *(const v4i*)(bP[nj] + 1024);
        }
        asm volatile("s_waitcnt vmcnt(0)" ::: "memory");
        __builtin_amdgcn_s_barrier();
#pragma unroll
        for (int i = 0; i < 4; ++i) {
            aLo[i][0] = *(const v4i*)(smem + aRB + i * 2048 + chnk0);
            aLo[i][1] = *(const v4i*)(smem + aRB + i * 2048 + chnk1);
        }
    }

    for (int seg = 0; seg < 2; ++seg) {
        const int bm = bmBase + seg * 4;
        const int8_t* aT0 = Xq + (size_t)bm * BM * K;

        for (int kt = 0; kt < KT; ++kt) {
            const int Ab  = (kt & 1) * 32768;
            const int nAb = Ab ^ 32768;
            const bool more = (kt + 1 < KT);
            const bool pf   = more || (seg == 0);
            const int8_t* aTn = more ? aT0 + (size_t)(kt + 1) * BKB
                                     : Xq + (size_t)(bmBase + 4) * BM * K;
            const int bOffN = more ? (kt + 1) * 2048 : 0;   // packed-B kt stride

            // ---- P0: stage A(next); MFMA (aLo x bF[0,1])
            if (pf) { STAGE(aTn, nAb, 0);   STAGE(aTn, nAb, 64);
                      STAGE(aTn, nAb, 128); STAGE(aTn, nAb, 192); }
            __builtin_amdgcn_s_setprio(1);
#pragma unroll
            for (int i = 0; i < 4; ++i)
#pragma unroll
                for (int j = 0; j < 2; ++j) {
                    acc[i][j] = MFMA(aLo[i][0], bF[j][0], acc[i][j], 0, 0, 0);
                    acc[i][j] = MFMA(aLo[i][1], bF[j][1], acc[i][j], 0, 0, 0);
                }
            __builtin_amdgcn_s_setprio(0);

            // ---- P1: read aHi (cur buf); MFMA (aLo x bF[2,3])
#pragma unroll
            for (int i = 0; i < 4; ++i) {
                aHi[i][0] = *(const v4i*)(smem + Ab + aRB + 16384 + i * 2048 + chnk0);
                aHi[i][1] = *(const v4i*)(smem + Ab + aRB + 16384 + i * 2048 + chnk1);
            }
            __builtin_amdgcn_s_setprio(1);
#pragma unroll
            for (int i = 0; i < 4; ++i)
#pragma unroll
                for (int j = 0; j < 2; ++j) {
                    acc[i][2 + j] = MFMA(aLo[i][0], bF[2 + j][0], acc[i][2 + j], 0, 0, 0);
                    acc[i][2 + j] = MFMA(aLo[i][1], bF[2 + j][1], acc[i][2 + j], 0, 0, 0);
                }
            __builtin_amdgcn_s_setprio(0);

            // ---- P2: MFMA (aHi x bF[0,1]); per-kt sync
            __builtin_amdgcn_s_setprio(1);
#pragma unroll
            for (int i = 0; i < 4; ++i)
#pragma unroll
                for (int j = 0; j < 2; ++j) {
                    acc[4 + i][j] = MFMA(aHi[i][0], bF[j][0], acc[4 + i][j], 0, 0, 0);
                    acc[4 + i][j] = MFMA(aHi[i][1], bF[j][1], acc[4 + i][j], 0, 0, 0);
                }
            __builtin_amdgcn_s_setprio(0);
            asm volatile("s_waitcnt vmcnt(0)" ::: "memory");  // A stages landed
            __builtin_amdgcn_s_barrier();

            // ---- P3: load bF[0,1](next); read aLo(next); MFMA (aHi x bF[2,3]);
            //          load bF[2,3](next)
            if (pf) {
#pragma unroll
                for (int j = 0; j < 2; ++j) {
                    bF[j][0] = *(const v4i*)(bP[j] + bOffN);
                    bF[j][1] = *(const v4i*)(bP[j] + bOffN + 1024);
                }
#pragma unroll
                for (int i = 0; i < 4; ++i) {
                    aLo[i][0] = *(const v4i*)(smem + nAb + aRB + i * 2048 + chnk0);
                    aLo[i][1] = *(const v4i*)(smem + nAb + aRB + i * 2048 + chnk1);
                }
            }
            __builtin_amdgcn_s_setprio(1);
#pragma unroll
            for (int i = 0; i < 4; ++i)
#pragma unroll
                for (int j = 0; j < 2; ++j) {
                    acc[4 + i][2 + j] = MFMA(aHi[i][0], bF[2 + j][0], acc[4 + i][2 + j], 0, 0, 0);
                    acc[4 + i][2 + j] = MFMA(aHi[i][1], bF[2 + j][1], acc[4 + i][2 + j], 0, 0, 0);
                }
            __builtin_amdgcn_s_setprio(0);
            if (pf) {
#pragma unroll
                for (int j = 0; j < 2; ++j) {
                    bF[2 + j][0] = *(const v4i*)(bP[2 + j] + bOffN);
                    bF[2 + j][1] = *(const v4i*)(bP[2 + j] + bOffN + 1024);
                }
            }
        }

        // ----- epilogue: dequant + bias (layout col=lane&15, row=(lane>>4)*4+reg)
        {
            float wsv[4], bv[4];
#pragma unroll
            for (int j = 0; j < 4; ++j) {
                const int n = bn * BN + ((j >> 1) << 7) + (wcol << 5) + ((j & 1) << 4) + col;
                wsv[j] = ws[n];
                bv[j]  = bias[n];
            }
#pragma unroll
            for (int i = 0; i < 8; ++i) {
                const int mbase = bm * BM + ((i >> 2) << 7) + (wrow << 6) + ((i & 3) << 4) + rowb;
#pragma unroll
                for (int r = 0; r < 4; ++r) {
                    const int m = mbase + r;
                    const float xsm = xs[m];
                    float* yrow = Y + (size_t)m * N;
#pragma unroll
                    for (int j = 0; j < 4; ++j) {
                        const int n = bn * BN + ((j >> 1) << 7) + (wcol << 5) + ((j & 1) << 4) + col;
                        yrow[n] = (float)acc[i][j][r] * xsm * wsv[j] + bv[j];
                    }
                }
            }
        }

        if (seg == 0) {
#pragma unroll
            for (int i = 0; i < 8; ++i)
#pragma unroll
                for (int j = 0; j < 4; ++j)
                    acc[i][j] = (v4i){0, 0, 0, 0};
        }
    }
}

// ---------------------------------------------------------------------------
extern "C" void kernel_launch(void* const* d_in, const int* in_sizes, int n_in,
                              void* d_out, int out_size, void* d_ws, size_t ws_size,
                              hipStream_t stream) {
    const float* X    = (const float*)d_in[0];
    const float* W    = (const float*)d_in[1];
    const float* bias = (const float*)d_in[2];
    const float* ss   = (const float*)d_in[3];

    const int DIN  = in_sizes[3];              // 4096
    const int DOUT = in_sizes[2];              // 4096
    const int M    = in_sizes[0] / DIN;        // 8192

    int8_t* Xq = (int8_t*)d_ws;
    int8_t* Wq = Xq + (size_t)M * DIN;         // packed layout, same size
    float*  xs = (float*)(Wq + (size_t)DOUT * DIN);
    float*  ws = xs + M;
    float*  Y  = (float*)d_out;

    quant_kernel<<<M + DOUT, 256, 0, stream>>>(X, W, ss, Xq, xs, Wq, ws, DIN, M);
    gemm_i8_kernel<<<(M / BM) * (DOUT / BN) / 2, 512, 0, stream>>>(Xq, Wq, xs, ws, bias, Y, M, DOUT, DIN);
}

// Round 14
// 185.110 us; speedup vs baseline: 1.0590x; 1.0590x over previous
//
#include <hip/hip_runtime.h>
#include <stdint.h>

typedef int v4i __attribute__((ext_vector_type(4)));

#define EPS_F32 1.1920928955078125e-07f   // np.finfo(float32).eps = 2^-23

// ---------------------------------------------------------------------------
// Fused quant kernel: blocks [0,M) do per-token X quant, blocks [M,M+DOUT)
// do per-out-channel W quant.  Row-major outputs (r10 version).
// ---------------------------------------------------------------------------
__global__ __launch_bounds__(256) void quant_kernel(
    const float* __restrict__ X, const float* __restrict__ W,
    const float* __restrict__ ss,
    int8_t* __restrict__ Xq, float* __restrict__ xs,
    int8_t* __restrict__ Wq, float* __restrict__ ws,
    int DIN, int M)
{
    const int bid = blockIdx.x;
    const int tid = threadIdx.x;
    const bool isX = bid < M;
    const float* row = isX ? X + (size_t)bid * DIN
                           : W + (size_t)(bid - M) * DIN;

    float4 v[4];
    float amax = 0.f;
#pragma unroll
    for (int c = 0; c < 4; ++c) {
        const int k = c * 1024 + tid * 4;
        float4 xv = *(const float4*)(row + k);
        float4 sv = *(const float4*)(ss + k);
        float4 q;
        if (isX) { q.x = xv.x / sv.x; q.y = xv.y / sv.y;
                   q.z = xv.z / sv.z; q.w = xv.w / sv.w; }
        else     { q.x = xv.x * sv.x; q.y = xv.y * sv.y;
                   q.z = xv.z * sv.z; q.w = xv.w * sv.w; }
        v[c] = q;
        amax = fmaxf(amax, fmaxf(fmaxf(fabsf(q.x), fabsf(q.y)),
                                 fmaxf(fabsf(q.z), fabsf(q.w))));
    }
    __shared__ float red[4];
    for (int off = 32; off; off >>= 1) amax = fmaxf(amax, __shfl_xor(amax, off));
    const int lane = tid & 63, w = tid >> 6;
    if (lane == 0) red[w] = amax;
    __syncthreads();
    amax = fmaxf(fmaxf(red[0], red[1]), fmaxf(red[2], red[3]));

    float scale, lo;
    if (isX) { scale = fmaxf(amax, 1e-5f) / 127.0f;      lo = -127.f; }
    else     { scale = fmaxf(amax / 127.5f, EPS_F32);    lo = -128.f; }
    if (tid == 0) { if (isX) xs[bid] = scale; else ws[bid - M] = scale; }

    int* qout = isX ? (int*)(Xq + (size_t)bid * DIN)
                    : (int*)(Wq + (size_t)(bid - M) * DIN);
#pragma unroll
    for (int c = 0; c < 4; ++c) {
        float4 q = v[c];
        int b0 = (int)fminf(fmaxf(rintf(q.x / scale), lo), 127.f);
        int b1 = (int)fminf(fmaxf(rintf(q.y / scale), lo), 127.f);
        int b2 = (int)fminf(fmaxf(rintf(q.z / scale), lo), 127.f);
        int b3 = (int)fminf(fmaxf(rintf(q.w / scale), lo), 127.f);
        qout[c * 256 + tid] = (b0 & 255) | ((b1 & 255) << 8) |
                              ((b2 & 255) << 16) | ((b3 & 255) << 24);
    }
}

// ---------------------------------------------------------------------------
// Persistent 2-tile int8 NT GEMM, 256x256 tiles, BKB=128, 8 waves (2x4),
// 128 KiB dbuf LDS, mfma_i32_16x16x64_i8.  Grid = 256 (1 block/CU).
//
// ROUND 14 = round-7 kernel (132us, passing) + WAVE ANTI-PHASING:
// waves with wrow==1 (w>=4; round-robin wave->SIMD assignment puts w and
// w+4 on the same SIMD, so this splits each SIMD's wave pair) execute each
// phase as {MFMA cluster -> reads -> stages}; wrow==0 waves keep the r7
// order {reads -> stages -> MFMA}.  At any instant ~half the waves feed
// the matrix pipes while the other half feed the LDS port, breaking the
// in-phase equilibrium (both-pipes-at-55% symptom of r7/r9/r10/r12).
// Correctness-neutral: same reads/MFMAs/stages per wave, same per-wave
// barrier & vmcnt counts (barriers + vmcnt are OUTSIDE the if/else);
// reordering is confined to barrier-free regions; all reads target
// published buffers.  Branch is wave-uniform (no divergence).
//
// Phase map (even = r7): P0 {read bHi | stage x4 | MFMA lo,lo}
//                        P1 {read aHi | stage x4 | MFMA lo,hi}
//                        P2 {MFMA hi,lo} vmcnt(0)+barrier
//                        P3 {read aLo/bLo(next) | MFMA hi,hi}
// Sync audit identical to round 7 (passing).
// ---------------------------------------------------------------------------
#define BM 256
#define BN 256
#define BKB 128

#define MFMA __builtin_amdgcn_mfma_i32_16x16x64_i8

__global__ __launch_bounds__(512, 2) void gemm_i8_kernel(
    const int8_t* __restrict__ Xq, const int8_t* __restrict__ Wq,
    const float* __restrict__ xs, const float* __restrict__ ws,
    const float* __restrict__ bias, float* __restrict__ Y,
    int M, int N, int K)
{
    __shared__ __align__(16) int8_t smem[131072];

    const int tid  = threadIdx.x;
    const int lane = tid & 63;
    const int w    = tid >> 6;
    const int wrow = w >> 2, wcol = w & 3;
    const bool anti = (wrow == 1);   // anti-phase half (same-SIMD partner of wrow0)

    // 256 blocks; XCD-aware: each XCD owns an 8x8 rect of the 32x16 tile grid.
    const int bid    = blockIdx.x;
    const int xcd    = bid & 7, idx = bid >> 3;        // idx in [0,32)
    const int bmBase = (xcd >> 1) * 8 + (idx >> 3);    // seg0 bm; seg1 = +4
    const int bn     = (xcd & 1) * 8 + (idx & 7);

    const int srcSwz = ((lane & 7) ^ (lane >> 3)) << 4;  // staging source swizzle
    const int chnk0  = ((lane >> 4) ^ (lane & 7)) << 4;  // frag read, k-slice 0
    const int chnk1  = chnk0 ^ 64;                       // k-slice 1
    const int aRB = ((wrow << 6) + (lane & 15)) << 7;    // A frag row-byte base
    const int bRB = ((wcol << 5) + (lane & 15)) << 7;    // B frag row-byte base

    auto STAGE = [&](const int8_t* gtile, int region, int rowStart) {
        const int8_t* src = gtile +
            (size_t)(rowStart + (w << 3) + (lane >> 3)) * K + srcSwz;
        __builtin_amdgcn_global_load_lds(
            (const __attribute__((address_space(1))) void*)src,
            (__attribute__((address_space(3))) void*)(smem + region + ((rowStart + (w << 3)) << 7)),
            16, 0, 0);
    };

    v4i acc[8][4] = {};
    v4i aLo[4][2], aHi[4][2], bLo[2][2], bHi[2][2];

    const int KT = K / BKB;   // 32
    const int8_t* bT0 = Wq + (size_t)bn * BN * K;   // same B panel both segs
    const int rowb = (lane >> 4) << 2;
    const int col  = lane & 15;

    // prologue: stage tile (seg0,kt0) into buf0; initial aLo/bLo reads
    {
        const int8_t* aT0 = Xq + (size_t)bmBase * BM * K;
        STAGE(aT0, 0,     0);   STAGE(aT0, 0,     64);
        STAGE(aT0, 0,     128); STAGE(aT0, 0,     192);
        STAGE(bT0, 32768, 0);   STAGE(bT0, 32768, 64);
        STAGE(bT0, 32768, 128); STAGE(bT0, 32768, 192);
        asm volatile("s_waitcnt vmcnt(0)" ::: "memory");
        __builtin_amdgcn_s_barrier();
#pragma unroll
        for (int i = 0; i < 4; ++i) {
            aLo[i][0] = *(const v4i*)(smem + aRB + i * 2048 + chnk0);
            aLo[i][1] = *(const v4i*)(smem + aRB + i * 2048 + chnk1);
        }
#pragma unroll
        for (int j = 0; j < 2; ++j) {
            bLo[j][0] = *(const v4i*)(smem + 32768 + bRB + j * 2048 + chnk0);
            bLo[j][1] = *(const v4i*)(smem + 32768 + bRB + j * 2048 + chnk1);
        }
    }

    for (int seg = 0; seg < 2; ++seg) {
        const int bm = bmBase + seg * 4;
        const int8_t* aT0 = Xq + (size_t)bm * BM * K;

        for (int kt = 0; kt < KT; ++kt) {
            const int Ab  = (kt & 1) * 65536;
            const int Bb  = Ab + 32768;
            const int nAb = ((kt & 1) ^ 1) * 65536;
            const int nBb = nAb + 32768;
            const bool more = (kt + 1 < KT);
            const bool pf   = more || (seg == 0);
            const int8_t* aTn = more ? aT0 + (size_t)(kt + 1) * BKB
                                     : Xq + (size_t)(bmBase + 4) * BM * K;
            const int8_t* bTn = more ? bT0 + (size_t)(kt + 1) * BKB : bT0;

            auto READ_BHI = [&] {
#pragma unroll
                for (int j = 0; j < 2; ++j) {
                    bHi[j][0] = *(const v4i*)(smem + Bb + bRB + 16384 + j * 2048 + chnk0);
                    bHi[j][1] = *(const v4i*)(smem + Bb + bRB + 16384 + j * 2048 + chnk1);
                }
            };
            auto READ_AHI = [&] {
#pragma unroll
                for (int i = 0; i < 4; ++i) {
                    aHi[i][0] = *(const v4i*)(smem + Ab + aRB + 16384 + i * 2048 + chnk0);
                    aHi[i][1] = *(const v4i*)(smem + Ab + aRB + 16384 + i * 2048 + chnk1);
                }
            };
            auto READ_LO_NEXT = [&] {
                if (pf) {
#pragma unroll
                    for (int i = 0; i < 4; ++i) {
                        aLo[i][0] = *(const v4i*)(smem + nAb + aRB + i * 2048 + chnk0);
                        aLo[i][1] = *(const v4i*)(smem + nAb + aRB + i * 2048 + chnk1);
                    }
#pragma unroll
                    for (int j = 0; j < 2; ++j) {
                        bLo[j][0] = *(const v4i*)(smem + nBb + bRB + j * 2048 + chnk0);
                        bLo[j][1] = *(const v4i*)(smem + nBb + bRB + j * 2048 + chnk1);
                    }
                }
            };
            auto STAGE_P0 = [&] {
                if (pf) { STAGE(aTn, nAb, 0); STAGE(aTn, nAb, 64);
                          STAGE(bTn, nBb, 0); STAGE(bTn, nBb, 64); }
            };
            auto STAGE_P1 = [&] {
                if (pf) { STAGE(bTn, nBb, 128); STAGE(bTn, nBb, 192);
                          STAGE(aTn, nAb, 128); STAGE(aTn, nAb, 192); }
            };
            auto M_LL = [&] {
                __builtin_amdgcn_s_setprio(1);
#pragma unroll
                for (int i = 0; i < 4; ++i)
#pragma unroll
                    for (int j = 0; j < 2; ++j) {
                        acc[i][j] = MFMA(aLo[i][0], bLo[j][0], acc[i][j], 0, 0, 0);
                        acc[i][j] = MFMA(aLo[i][1], bLo[j][1], acc[i][j], 0, 0, 0);
                    }
                __builtin_amdgcn_s_setprio(0);
            };
            auto M_LH = [&] {
                __builtin_amdgcn_s_setprio(1);
#pragma unroll
                for (int i = 0; i < 4; ++i)
#pragma unroll
                    for (int j = 0; j < 2; ++j) {
                        acc[i][2 + j] = MFMA(aLo[i][0], bHi[j][0], acc[i][2 + j], 0, 0, 0);
                        acc[i][2 + j] = MFMA(aLo[i][1], bHi[j][1], acc[i][2 + j], 0, 0, 0);
                    }
                __builtin_amdgcn_s_setprio(0);
            };
            auto M_HL = [&] {
                __builtin_amdgcn_s_setprio(1);
#pragma unroll
                for (int i = 0; i < 4; ++i)
#pragma unroll
                    for (int j = 0; j < 2; ++j) {
                        acc[4 + i][j] = MFMA(aHi[i][0], bLo[j][0], acc[4 + i][j], 0, 0, 0);
                        acc[4 + i][j] = MFMA(aHi[i][1], bLo[j][1], acc[4 + i][j], 0, 0, 0);
                    }
                __builtin_amdgcn_s_setprio(0);
            };
            auto M_HH = [&] {
                __builtin_amdgcn_s_setprio(1);
#pragma unroll
                for (int i = 0; i < 4; ++i)
#pragma unroll
                    for (int j = 0; j < 2; ++j) {
                        acc[4 + i][2 + j] = MFMA(aHi[i][0], bHi[j][0], acc[4 + i][2 + j], 0, 0, 0);
                        acc[4 + i][2 + j] = MFMA(aHi[i][1], bHi[j][1], acc[4 + i][2 + j], 0, 0, 0);
                    }
                __builtin_amdgcn_s_setprio(0);
            };

            // ---- P0
            if (anti) { M_LL(); READ_BHI(); STAGE_P0(); }
            else      { READ_BHI(); STAGE_P0(); M_LL(); }
            // ---- P1
            if (anti) { M_LH(); READ_AHI(); STAGE_P1(); }
            else      { READ_AHI(); STAGE_P1(); M_LH(); }
            // ---- P2 + per-kt sync (uniform)
            M_HL();
            asm volatile("s_waitcnt vmcnt(0)" ::: "memory");  // all 8 stages landed
            __builtin_amdgcn_s_barrier();
            // ---- P3
            if (anti) { M_HH(); READ_LO_NEXT(); }
            else      { READ_LO_NEXT(); M_HH(); }
        }

        // ----- epilogue: dequant + bias (layout col=lane&15, row=(lane>>4)*4+reg)
        {
            float wsv[4], bv[4];
#pragma unroll
            for (int j = 0; j < 4; ++j) {
                const int n = bn * BN + ((j >> 1) << 7) + (wcol << 5) + ((j & 1) << 4) + col;
                wsv[j] = ws[n];
                bv[j]  = bias[n];
            }
#pragma unroll
            for (int i = 0; i < 8; ++i) {
                const int mbase = bm * BM + ((i >> 2) << 7) + (wrow << 6) + ((i & 3) << 4) + rowb;
#pragma unroll
                for (int r = 0; r < 4; ++r) {
                    const int m = mbase + r;
                    const float xsm = xs[m];
                    float* yrow = Y + (size_t)m * N;
#pragma unroll
                    for (int j = 0; j < 4; ++j) {
                        const int n = bn * BN + ((j >> 1) << 7) + (wcol << 5) + ((j & 1) << 4) + col;
                        yrow[n] = (float)acc[i][j][r] * xsm * wsv[j] + bv[j];
                    }
                }
            }
        }

        if (seg == 0) {
#pragma unroll
            for (int i = 0; i < 8; ++i)
#pragma unroll
                for (int j = 0; j < 4; ++j)
                    acc[i][j] = (v4i){0, 0, 0, 0};
        }
    }
}

// ---------------------------------------------------------------------------
extern "C" void kernel_launch(void* const* d_in, const int* in_sizes, int n_in,
                              void* d_out, int out_size, void* d_ws, size_t ws_size,
                              hipStream_t stream) {
    const float* X    = (const float*)d_in[0];
    const float* W    = (const float*)d_in[1];
    const float* bias = (const float*)d_in[2];
    const float* ss   = (const float*)d_in[3];

    const int DIN  = in_sizes[3];              // 4096
    const int DOUT = in_sizes[2];              // 4096
    const int M    = in_sizes[0] / DIN;        // 8192

    int8_t* Xq = (int8_t*)d_ws;
    int8_t* Wq = Xq + (size_t)M * DIN;
    float*  xs = (float*)(Wq + (size_t)DOUT * DIN);
    float*  ws = xs + M;
    float*  Y  = (float*)d_out;

    quant_kernel<<<M + DOUT, 256, 0, stream>>>(X, W, ss, Xq, xs, Wq, ws, DIN, M);
    gemm_i8_kernel<<<(M / BM) * (DOUT / BN) / 2, 512, 0, stream>>>(Xq, Wq, xs, ws, bias, Y, M, DOUT, DIN);
}